// Round 1
// baseline (1026.873 us; speedup 1.0000x reference)
//
#include <hip/hip_runtime.h>
#include <math.h>

#define H    768
#define H4   192            // H/4
#define DIM  128
#define LQ   32
#define LD   512
#define TT   16             // doc-token tile
#define QSTR 132            // DIM + 4 padding (bank-conflict break)
#define EPSF 1e-12f

// ---------------- query projection + L2 normalize ----------------
// grid = Bq*Lq blocks, 128 threads; thread d computes one output dim.
__global__ __launch_bounds__(128) void qproj_kernel(
    const float* __restrict__ qh, const float* __restrict__ W,
    float* __restrict__ qn)
{
    const int tok = blockIdx.x;
    const int tid = threadIdx.x;
    __shared__ float row[H];
    __shared__ float red[128];

    const float4* src  = (const float4*)(qh + (size_t)tok * H);
    float4*       row4 = (float4*)row;
    for (int i = tid; i < H4; i += 128) row4[i] = src[i];
    __syncthreads();

    const float4* w4 = (const float4*)(W + (size_t)tid * H);
    float acc = 0.f;
    #pragma unroll 4
    for (int i = 0; i < H4; ++i) {
        float4 w = w4[i]; float4 x = row4[i];
        acc += w.x*x.x + w.y*x.y + w.z*x.z + w.w*x.w;
    }
    red[tid] = acc * acc;
    __syncthreads();
    for (int s = 64; s > 0; s >>= 1) {
        if (tid < s) red[tid] += red[tid + s];
        __syncthreads();
    }
    const float inv = 1.0f / fmaxf(sqrtf(red[0]), EPSF);
    qn[(size_t)tok * DIM + tid] = acc * inv;
}

// ---------------- fused doc projection + norm + masked MaxSim ----------------
// grid = Bd blocks (one doc each), 256 threads.
__global__ __launch_bounds__(256) void doc_kernel(
    const float* __restrict__ dh, const float* __restrict__ W,
    const int* __restrict__ dmask, const float* __restrict__ qn,
    float* __restrict__ out, const int* __restrict__ ppq_p)
{
    const int b   = blockIdx.x;
    const int tid = threadIdx.x;
    const int ppq = ppq_p[0];

    __shared__ float dld[TT][H];       // 48 KB  staged d_hidden tile
    __shared__ float qld[LQ][QSTR];    // 16.5 KB normalized queries
    __shared__ float pn[TT][QSTR];     // 8.25 KB raw projections
    __shared__ float dinv[TT];
    __shared__ int   mk[TT];
    __shared__ float smax[LQ][8];
    __shared__ float colmax[LQ];

    // load this doc's query block (b/ppq) into LDS
    const float* qb = qn + (size_t)(b / ppq) * LQ * DIM;
    for (int i = tid; i < LQ * DIM; i += 256) qld[i >> 7][i & 127] = qb[i];

    const int d   = tid & 127;   // output dim for projection
    const int sub = tid >> 7;    // token parity group
    const int qi  = tid >> 3;    // query index for sim step
    const int ts  = tid & 7;     // token slot for sim step
    float tmax0 = -INFINITY, tmax1 = -INFINITY;

    const float4* Wrow  = (const float4*)(W + (size_t)d * H);
    const float*  dbase = dh + (size_t)b * LD * H;

    __syncthreads();

    for (int t0 = 0; t0 < LD; t0 += TT) {
        // ---- stage d_hidden [TT][H] (coalesced float4) ----
        const float4* src = (const float4*)(dbase + (size_t)t0 * H);
        float4*       dst = (float4*)&dld[0][0];
        for (int i = tid; i < TT * H4; i += 256) dst[i] = src[i];
        if (tid < TT) mk[tid] = dmask[b * LD + t0 + tid];
        __syncthreads();

        // ---- projection: thread (d,sub) -> tokens {sub+2j} ----
        float acc[8];
        #pragma unroll
        for (int j = 0; j < 8; ++j) acc[j] = 0.f;
        for (int i = 0; i < H4; ++i) {
            float4 w = Wrow[i];
            #pragma unroll
            for (int j = 0; j < 8; ++j) {
                float4 x = ((const float4*)&dld[sub + 2*j][0])[i];
                acc[j] += w.x*x.x + w.y*x.y + w.z*x.z + w.w*x.w;
            }
        }
        #pragma unroll
        for (int j = 0; j < 8; ++j) pn[sub + 2*j][d] = acc[j];
        __syncthreads();

        // ---- per-token inverse norm: 16 lanes per token ----
        {
            const int t = tid >> 4, l = tid & 15;
            float s = 0.f;
            #pragma unroll
            for (int j = 0; j < 8; ++j) { float v = pn[t][l + 16*j]; s += v*v; }
            #pragma unroll
            for (int m = 8; m > 0; m >>= 1) s += __shfl_xor(s, m, 64);
            if (l == 0) dinv[t] = 1.0f / fmaxf(sqrtf(s), EPSF);
        }
        __syncthreads();

        // ---- sim + masked running max: thread (qi, ts) handles tokens ts, ts+8
        {
            const float4* qv = (const float4*)&qld[qi][0];
            const float4* p0 = (const float4*)&pn[ts][0];
            const float4* p1 = (const float4*)&pn[ts + 8][0];
            float s0 = 0.f, s1 = 0.f;
            #pragma unroll 8
            for (int k = 0; k < 32; ++k) {
                float4 q = qv[k];
                float4 a = p0[k], c = p1[k];
                s0 += q.x*a.x + q.y*a.y + q.z*a.z + q.w*a.w;
                s1 += q.x*c.x + q.y*c.y + q.z*c.z + q.w*c.w;
            }
            if (mk[ts])     tmax0 = fmaxf(tmax0, s0 * dinv[ts]);
            if (mk[ts + 8]) tmax1 = fmaxf(tmax1, s1 * dinv[ts + 8]);
        }
        __syncthreads();
    }

    // ---- final reduce: max over token-slots, sum over queries ----
    smax[qi][ts] = fmaxf(tmax0, tmax1);
    __syncthreads();
    if (tid < LQ) {
        float m = smax[tid][0];
        #pragma unroll
        for (int j = 1; j < 8; ++j) m = fmaxf(m, smax[tid][j]);
        colmax[tid] = m;
    }
    __syncthreads();
    if (tid == 0) {
        float s = 0.f;
        for (int j = 0; j < LQ; ++j) s += colmax[j];
        out[b] = s;
    }
}

extern "C" void kernel_launch(void* const* d_in, const int* in_sizes, int n_in,
                              void* d_out, int out_size, void* d_ws, size_t ws_size,
                              hipStream_t stream) {
    const float* qh    = (const float*)d_in[0];
    const float* dh    = (const float*)d_in[1];
    const float* W     = (const float*)d_in[2];
    const int*   dmask = (const int*)d_in[3];
    const int*   ppq   = (const int*)d_in[4];
    float*       out   = (float*)d_out;
    float*       qn    = (float*)d_ws;   // Bq*Lq*DIM floats = 512 KB

    const int nq = in_sizes[0] / H;      // Bq*Lq = 1024 query tokens
    const int Bd = out_size;             // 256 docs

    qproj_kernel<<<nq, 128, 0, stream>>>(qh, W, qn);
    doc_kernel<<<Bd, 256, 0, stream>>>(dh, W, dmask, qn, out, ppq);
}

// Round 2
// 333.729 us; speedup vs baseline: 3.0770x; 3.0770x over previous
//
#include <hip/hip_runtime.h>
#include <math.h>

#define H    768
#define H4   192
#define DIM  128
#define LQ   32
#define LD   512
#define EPSF 1e-12f
#define CP   136   // C row pad (bf16 elements): 272 B rows, 16B-aligned

typedef short bf16x8 __attribute__((ext_vector_type(8)));
typedef float f32x4  __attribute__((ext_vector_type(4)));

static __device__ __forceinline__ unsigned short f2bf(float x) {
    unsigned u = __float_as_uint(x);
    u += 0x7FFFu + ((u >> 16) & 1u);          // round-to-nearest-even
    return (unsigned short)(u >> 16);
}
static __device__ __forceinline__ float bf2f(unsigned short h) {
    return __uint_as_float(((unsigned)h) << 16);
}

// ---------------- query projection + L2 normalize -> bf16 ----------------
__global__ __launch_bounds__(128) void qproj_kernel(
    const float* __restrict__ qh, const float* __restrict__ W,
    unsigned short* __restrict__ qn)
{
    const int tok = blockIdx.x;
    const int tid = threadIdx.x;
    __shared__ float row[H];
    __shared__ float red[128];

    const float4* src  = (const float4*)(qh + (size_t)tok * H);
    float4*       row4 = (float4*)row;
    for (int i = tid; i < H4; i += 128) row4[i] = src[i];
    __syncthreads();

    const float4* w4 = (const float4*)(W + (size_t)tid * H);
    float acc = 0.f;
    #pragma unroll 4
    for (int i = 0; i < H4; ++i) {
        float4 w = w4[i]; float4 x = row4[i];
        acc += w.x*x.x + w.y*x.y + w.z*x.z + w.w*x.w;
    }
    red[tid] = acc * acc;
    __syncthreads();
    for (int s = 64; s > 0; s >>= 1) {
        if (tid < s) red[tid] += red[tid + s];
        __syncthreads();
    }
    const float inv = 1.0f / fmaxf(sqrtf(red[0]), EPSF);
    qn[(size_t)tok * DIM + tid] = f2bf(acc * inv);
}

// ---------------- doc: MFMA projection (bf16 hi/lo) + norm + masked MaxSim ----
union SmemU {
    struct {  // GEMM stage: 32 KB
        unsigned short Ah[128][32], Al[128][32], Wh[128][32], Wl[128][32];
    } g;
    struct {  // epilogue stage: ~45 KB
        unsigned short C[128][CP];
        unsigned short Q[32][CP];
        float dinv[128];
        int   mk[128];
        float pmax[32][4];
    } s;
};

__global__ __launch_bounds__(256) void docgemm_kernel(
    const float* __restrict__ dh, const float* __restrict__ W,
    const int* __restrict__ dmask, const unsigned short* __restrict__ qn,
    float* __restrict__ part, const int* __restrict__ ppq_p)
{
    __shared__ SmemU sm;
    const int blk = blockIdx.x;
    const int b   = blk >> 2;        // doc
    const int c   = blk & 3;         // 128-token chunk
    const int tid = threadIdx.x;
    const int w   = tid >> 6;        // wave 0..3
    const int wm  = w >> 1, wn = w & 1;
    const int l   = tid & 63;
    const int g   = l >> 4;
    const int r15 = l & 15;
    const int ppq = ppq_p[0];

    const float* Abase = dh + ((size_t)b * LD + (size_t)c * 128) * H;

    f32x4 acc[4][4];
    #pragma unroll
    for (int m = 0; m < 4; ++m)
        #pragma unroll
        for (int n = 0; n < 4; ++n)
            acc[m][n] = (f32x4){0.f, 0.f, 0.f, 0.f};

    for (int ks = 0; ks < H / 32; ++ks) {
        const int k0 = ks * 32;
        // ---- stage A (tokens) and W tiles: fp32 -> bf16 hi/lo, XOR-swizzled
        for (int idx = tid; idx < 2048; idx += 256) {
            const int which = idx >> 10;          // 0 = A, 1 = W
            const int i     = idx & 1023;
            const int row   = i >> 3;             // token (A) or dim (W)
            const int seg   = i & 7;              // float4 within 32-wide row
            const float4 v = which
                ? *(const float4*)(W     + (size_t)row * H + k0 + seg * 4)
                : *(const float4*)(Abase + (size_t)row * H + k0 + seg * 4);
            const float f[4] = {v.x, v.y, v.z, v.w};
            unsigned short hh[4], ll[4];
            #pragma unroll
            for (int j = 0; j < 4; ++j) {
                hh[j] = f2bf(f[j]);
                ll[j] = f2bf(f[j] - bf2f(hh[j]));
            }
            const int col = (seg * 4) ^ (((row >> 1) & 3) << 3);
            ushort4 vh = {hh[0], hh[1], hh[2], hh[3]};
            ushort4 vl = {ll[0], ll[1], ll[2], ll[3]};
            if (which) {
                *(ushort4*)&sm.g.Wh[row][col] = vh;
                *(ushort4*)&sm.g.Wl[row][col] = vl;
            } else {
                *(ushort4*)&sm.g.Ah[row][col] = vh;
                *(ushort4*)&sm.g.Al[row][col] = vl;
            }
        }
        __syncthreads();

        // ---- fragments + MFMA (hi*hi + hi*lo + lo*hi)
        bf16x8 ah[4], al[4];
        #pragma unroll
        for (int m = 0; m < 4; ++m) {
            const int row = wm * 64 + m * 16 + r15;
            const int sl  = (g ^ ((row >> 1) & 3)) * 8;
            ah[m] = *(const bf16x8*)&sm.g.Ah[row][sl];
            al[m] = *(const bf16x8*)&sm.g.Al[row][sl];
        }
        #pragma unroll
        for (int n = 0; n < 4; ++n) {
            const int row = wn * 64 + n * 16 + r15;
            const int sl  = (g ^ ((row >> 1) & 3)) * 8;
            bf16x8 bh = *(const bf16x8*)&sm.g.Wh[row][sl];
            bf16x8 bl = *(const bf16x8*)&sm.g.Wl[row][sl];
            #pragma unroll
            for (int m = 0; m < 4; ++m) {
                acc[m][n] = __builtin_amdgcn_mfma_f32_16x16x32_bf16(ah[m], bh, acc[m][n], 0, 0, 0);
                acc[m][n] = __builtin_amdgcn_mfma_f32_16x16x32_bf16(ah[m], bl, acc[m][n], 0, 0, 0);
                acc[m][n] = __builtin_amdgcn_mfma_f32_16x16x32_bf16(al[m], bh, acc[m][n], 0, 0, 0);
            }
        }
        __syncthreads();
    }

    // ---- epilogue: projected chunk -> LDS bf16 (C/D layout: row=(l>>4)*4+reg, col=l&15)
    #pragma unroll
    for (int m = 0; m < 4; ++m) {
        const int tok = wm * 64 + m * 16 + g * 4;
        #pragma unroll
        for (int n = 0; n < 4; ++n) {
            const int dim = wn * 64 + n * 16 + r15;
            #pragma unroll
            for (int r = 0; r < 4; ++r)
                sm.s.C[tok + r][dim] = f2bf(acc[m][n][r]);
        }
    }
    // queries (already bf16) -> LDS
    const unsigned short* qb = qn + (size_t)(b / ppq) * LQ * DIM;
    for (int idx = tid; idx < LQ * DIM / 4; idx += 256) {
        const int q = idx >> 5, seg = idx & 31;
        *(ushort4*)&sm.s.Q[q][seg * 4] = *(const ushort4*)(qb + q * DIM + seg * 4);
    }
    if (tid < 128) sm.s.mk[tid] = dmask[(size_t)b * LD + c * 128 + tid];
    __syncthreads();

    // ---- per-token inverse norm (2 threads/token)
    {
        const int t = tid >> 1, hf = tid & 1;
        float ssum = 0.f;
        #pragma unroll
        for (int j = 0; j < 8; ++j) {
            bf16x8 v = *(const bf16x8*)&sm.s.C[t][hf * 64 + j * 8];
            #pragma unroll
            for (int e = 0; e < 8; ++e) {
                float f = bf2f((unsigned short)v[e]);
                ssum += f * f;
            }
        }
        ssum += __shfl_xor(ssum, 1);
        if (hf == 0) sm.s.dinv[t] = 1.0f / fmaxf(sqrtf(ssum), EPSF);
    }
    __syncthreads();

    // ---- sim GEMM: [32 q] x [32 tokens per wave], K=128
    f32x4 sacc[2][2];
    #pragma unroll
    for (int m = 0; m < 2; ++m)
        #pragma unroll
        for (int n = 0; n < 2; ++n)
            sacc[m][n] = (f32x4){0.f, 0.f, 0.f, 0.f};
    #pragma unroll
    for (int ks = 0; ks < 4; ++ks) {
        bf16x8 qa[2], cb[2];
        #pragma unroll
        for (int m = 0; m < 2; ++m)
            qa[m] = *(const bf16x8*)&sm.s.Q[m * 16 + r15][ks * 32 + g * 8];
        #pragma unroll
        for (int n = 0; n < 2; ++n)
            cb[n] = *(const bf16x8*)&sm.s.C[w * 32 + n * 16 + r15][ks * 32 + g * 8];
        #pragma unroll
        for (int m = 0; m < 2; ++m)
            #pragma unroll
            for (int n = 0; n < 2; ++n)
                sacc[m][n] = __builtin_amdgcn_mfma_f32_16x16x32_bf16(qa[m], cb[n], sacc[m][n], 0, 0, 0);
    }

    // ---- masked per-query max over this wave's 32 tokens
    #pragma unroll
    for (int m = 0; m < 2; ++m) {
        #pragma unroll
        for (int r = 0; r < 4; ++r) {
            float vmax = -INFINITY;
            #pragma unroll
            for (int n = 0; n < 2; ++n) {
                const int t = w * 32 + n * 16 + r15;
                float v = sacc[m][n][r] * sm.s.dinv[t];
                v = sm.s.mk[t] ? v : -INFINITY;
                vmax = fmaxf(vmax, v);
            }
            #pragma unroll
            for (int off = 1; off < 16; off <<= 1)
                vmax = fmaxf(vmax, __shfl_xor(vmax, off));
            if (r15 == 0) sm.s.pmax[m * 16 + g * 4 + r][w] = vmax;
        }
    }
    __syncthreads();
    if (tid < 32) {
        float m0 = fmaxf(fmaxf(sm.s.pmax[tid][0], sm.s.pmax[tid][1]),
                         fmaxf(sm.s.pmax[tid][2], sm.s.pmax[tid][3]));
        part[(size_t)blk * 32 + tid] = m0;
    }
}

// ---------------- final: max over chunks, sum over queries ----------------
__global__ __launch_bounds__(64) void final_kernel(
    const float* __restrict__ part, float* __restrict__ out)
{
    const int b = blockIdx.x;
    const int q = threadIdx.x & 31;
    const float* p = part + (size_t)b * 128;
    float m = fmaxf(fmaxf(p[q], p[32 + q]), fmaxf(p[64 + q], p[96 + q]));
    #pragma unroll
    for (int off = 1; off < 32; off <<= 1) m += __shfl_xor(m, off);
    if (threadIdx.x == 0) out[b] = m;
}

extern "C" void kernel_launch(void* const* d_in, const int* in_sizes, int n_in,
                              void* d_out, int out_size, void* d_ws, size_t ws_size,
                              hipStream_t stream) {
    const float* qh    = (const float*)d_in[0];
    const float* dh    = (const float*)d_in[1];
    const float* W     = (const float*)d_in[2];
    const int*   dmask = (const int*)d_in[3];
    const int*   ppq   = (const int*)d_in[4];
    float*       out   = (float*)d_out;

    unsigned short* qn   = (unsigned short*)d_ws;                  // 1024*128 bf16 = 256 KB
    float*          part = (float*)((char*)d_ws + 262144);         // 1024*32 f32  = 128 KB

    const int nq = in_sizes[0] / H;      // Bq*Lq = 1024 query tokens
    const int Bd = out_size;             // 256 docs

    qproj_kernel<<<nq, 128, 0, stream>>>(qh, W, qn);
    docgemm_kernel<<<Bd * 4, 256, 0, stream>>>(dh, W, dmask, qn, part, ppq);
    final_kernel<<<Bd, 64, 0, stream>>>(part, out);
}

// Round 3
// 239.050 us; speedup vs baseline: 4.2956x; 1.3961x over previous
//
#include <hip/hip_runtime.h>
#include <math.h>

#define H    768
#define NT   24           // H/32 K-tiles
#define DIM  128
#define LQ   32
#define LD   512
#define EPSF 1e-12f

typedef short bf16x8 __attribute__((ext_vector_type(8)));
typedef float f32x4  __attribute__((ext_vector_type(4)));

static __device__ __forceinline__ unsigned short f2bf(float x) {
    unsigned u = __float_as_uint(x);
    u += 0x7FFFu + ((u >> 16) & 1u);          // round-to-nearest-even
    return (unsigned short)(u >> 16);
}
static __device__ __forceinline__ float bf2f(unsigned short h) {
    return __uint_as_float(((unsigned)h) << 16);
}

#define GLOAD_LDS16(g, l) __builtin_amdgcn_global_load_lds(                    \
    (const __attribute__((address_space(1))) unsigned int*)(const void*)(g),   \
    (__attribute__((address_space(3))) unsigned int*)(void*)(l), 16, 0, 0)

// ---------------- W -> bf16 hi/lo, pre-swizzled per K-tile ----------------
// ws layout: [ks][hi/lo][row 0..127][32 cols, slot-swizzled]  (16 KB per tile)
__global__ __launch_bounds__(256) void wconv_kernel(
    const float* __restrict__ W, unsigned short* __restrict__ wsW)
{
    const int ks  = blockIdx.x;
    const int tid = threadIdx.x;
    #pragma unroll 4
    for (int i = 0; i < 16; ++i) {
        const int idx = tid + i * 256;          // 0..4095
        const int row = idx >> 5, col = idx & 31;
        const float x = W[(size_t)row * H + ks * 32 + col];
        const unsigned short hi = f2bf(x);
        const unsigned short lo = f2bf(x - bf2f(hi));
        const int colS = (((col >> 3) ^ ((row >> 1) & 3)) << 3) | (col & 7);
        wsW[(((size_t)ks * 2 + 0) * 128 + row) * 32 + colS] = hi;
        wsW[(((size_t)ks * 2 + 1) * 128 + row) * 32 + colS] = lo;
    }
}

// ---------------- query projection + L2 normalize -> bf16 ----------------
__global__ __launch_bounds__(128) void qproj_kernel(
    const float* __restrict__ qh, const float* __restrict__ W,
    unsigned short* __restrict__ qn)
{
    const int tok = blockIdx.x;
    const int tid = threadIdx.x;
    __shared__ float row[H];
    __shared__ float red[128];

    const float4* src  = (const float4*)(qh + (size_t)tok * H);
    float4*       row4 = (float4*)row;
    for (int i = tid; i < H / 4; i += 128) row4[i] = src[i];
    __syncthreads();

    const float4* w4 = (const float4*)(W + (size_t)tid * H);
    float acc = 0.f;
    #pragma unroll 4
    for (int i = 0; i < H / 4; ++i) {
        float4 w = w4[i]; float4 x = row4[i];
        acc += w.x*x.x + w.y*x.y + w.z*x.z + w.w*x.w;
    }
    red[tid] = acc * acc;
    __syncthreads();
    for (int s = 64; s > 0; s >>= 1) {
        if (tid < s) red[tid] += red[tid + s];
        __syncthreads();
    }
    const float inv = 1.0f / fmaxf(sqrtf(red[0]), EPSF);
    qn[(size_t)tok * DIM + tid] = f2bf(acc * inv);
}

// ---------------- doc: pipelined MFMA projection + norm + masked MaxSim ----
union SmemU {
    struct {  // GEMM stage: 64 KB  [buf][hi/lo][row][32]
        unsigned short A[2][2][128][32];
        unsigned short Wt[2][2][128][32];
    } g;
    struct {  // epilogue stage: ~41.5 KB, XOR slot-swizzled rows
        unsigned short C[128][128];
        unsigned short Q[32][128];
        float dinv[128];
        int   mk[128];
        float pmax[32][4];
    } s;
};

__global__ __launch_bounds__(256) void docgemm_kernel(
    const float* __restrict__ dh, const unsigned short* __restrict__ wsW,
    const int* __restrict__ dmask, const unsigned short* __restrict__ qn,
    float* __restrict__ part, const int* __restrict__ ppq_p)
{
    __shared__ SmemU sm;
    const int blk = blockIdx.x;
    const int b   = blk >> 2;        // doc
    const int c   = blk & 3;         // 128-token chunk
    const int tid = threadIdx.x;
    const int w   = tid >> 6;        // wave 0..3
    const int wm  = w >> 1, wn = w & 1;
    const int l   = tid & 63;
    const int g   = l >> 4;
    const int r15 = l & 15;
    const int ppq = ppq_p[0];

    // A staging geometry: thread -> (row r0+i*32, 16-B segment seg0), i=0..3
    const int r0   = tid >> 3;
    const int seg0 = tid & 7;
    const int aswz = (r0 >> 1) & 3;                       // same for all i
    const int coli = (((seg0 >> 1) ^ aswz) << 3) | ((seg0 & 1) << 2);

    const float* Abase = dh + ((size_t)b * LD + (size_t)c * 128) * H;

    f32x4 acc[4][4];
    #pragma unroll
    for (int m = 0; m < 4; ++m)
        #pragma unroll
        for (int n = 0; n < 4; ++n)
            acc[m][n] = (f32x4){0.f, 0.f, 0.f, 0.f};

    float4 av[4];

    // ---- prologue: tile 0 ----
    {
        const char* wt   = (const char*)wsW;
        char*       wdst = (char*)&sm.g.Wt[0][0][0][0];
        #pragma unroll
        for (int cch = 0; cch < 4; ++cch) {
            const int off = (w * 4 + cch) * 1024;
            GLOAD_LDS16(wt + off + l * 16, wdst + off);
        }
        #pragma unroll
        for (int i = 0; i < 4; ++i)
            av[i] = *(const float4*)(Abase + (size_t)(r0 + i * 32) * H + seg0 * 4);
        #pragma unroll
        for (int i = 0; i < 4; ++i) {
            const int row = r0 + i * 32;
            const float f[4] = {av[i].x, av[i].y, av[i].z, av[i].w};
            ushort4 hi, lo;
            unsigned short* hp = (unsigned short*)&hi;
            unsigned short* lp = (unsigned short*)&lo;
            #pragma unroll
            for (int j = 0; j < 4; ++j) {
                hp[j] = f2bf(f[j]);
                lp[j] = f2bf(f[j] - bf2f(hp[j]));
            }
            *(ushort4*)&sm.g.A[0][0][row][coli] = hi;
            *(ushort4*)&sm.g.A[0][1][row][coli] = lo;
        }
        asm volatile("s_waitcnt vmcnt(0)" ::: "memory");
        __syncthreads();
    }

    // ---- main K-loop, 1-deep prefetch, one barrier per tile ----
    for (int t = 0; t < NT; ++t) {
        const int cur = t & 1, nxt = cur ^ 1;
        if (t + 1 < NT) {
            const int k0n = (t + 1) * 32;
            #pragma unroll
            for (int i = 0; i < 4; ++i)
                av[i] = *(const float4*)(Abase + (size_t)(r0 + i * 32) * H + k0n + seg0 * 4);
            const char* wt   = (const char*)(wsW + (size_t)(t + 1) * 2 * 128 * 32);
            char*       wdst = (char*)&sm.g.Wt[nxt][0][0][0];
            #pragma unroll
            for (int cch = 0; cch < 4; ++cch) {
                const int off = (w * 4 + cch) * 1024;
                GLOAD_LDS16(wt + off + l * 16, wdst + off);
            }
        }

        bf16x8 ah[4], al[4];
        #pragma unroll
        for (int m = 0; m < 4; ++m) {
            const int row = wm * 64 + m * 16 + r15;
            const int sl  = (g ^ ((row >> 1) & 3)) * 8;
            ah[m] = *(const bf16x8*)&sm.g.A[cur][0][row][sl];
            al[m] = *(const bf16x8*)&sm.g.A[cur][1][row][sl];
        }
        #pragma unroll
        for (int n = 0; n < 4; ++n) {
            const int row = wn * 64 + n * 16 + r15;
            const int sl  = (g ^ ((row >> 1) & 3)) * 8;
            bf16x8 bh = *(const bf16x8*)&sm.g.Wt[cur][0][row][sl];
            bf16x8 bl = *(const bf16x8*)&sm.g.Wt[cur][1][row][sl];
            #pragma unroll
            for (int m = 0; m < 4; ++m) {
                acc[m][n] = __builtin_amdgcn_mfma_f32_16x16x32_bf16(ah[m], bh, acc[m][n], 0, 0, 0);
                acc[m][n] = __builtin_amdgcn_mfma_f32_16x16x32_bf16(ah[m], bl, acc[m][n], 0, 0, 0);
                acc[m][n] = __builtin_amdgcn_mfma_f32_16x16x32_bf16(al[m], bh, acc[m][n], 0, 0, 0);
            }
        }

        if (t + 1 < NT) {
            #pragma unroll
            for (int i = 0; i < 4; ++i) {
                const int row = r0 + i * 32;
                const float f[4] = {av[i].x, av[i].y, av[i].z, av[i].w};
                ushort4 hi, lo;
                unsigned short* hp = (unsigned short*)&hi;
                unsigned short* lp = (unsigned short*)&lo;
                #pragma unroll
                for (int j = 0; j < 4; ++j) {
                    hp[j] = f2bf(f[j]);
                    lp[j] = f2bf(f[j] - bf2f(hp[j]));
                }
                *(ushort4*)&sm.g.A[nxt][0][row][coli] = hi;
                *(ushort4*)&sm.g.A[nxt][1][row][coli] = lo;
            }
        }
        asm volatile("s_waitcnt vmcnt(0)" ::: "memory");
        __syncthreads();
    }

    // ---- epilogue: C (bf16, swizzled) ----
    #pragma unroll
    for (int m = 0; m < 4; ++m) {
        const int tokb = wm * 64 + m * 16 + g * 4;
        #pragma unroll
        for (int n = 0; n < 4; ++n) {
            const int dim = wn * 64 + n * 16 + r15;
            #pragma unroll
            for (int r = 0; r < 4; ++r) {
                const int tok  = tokb + r;
                const int slot = (dim >> 3) ^ (tok & 7);
                sm.s.C[tok][slot * 8 + (dim & 7)] = f2bf(acc[m][n][r]);
            }
        }
    }
    const unsigned short* qb = qn + (size_t)(b / ppq) * LQ * DIM;
    for (int idx = tid; idx < LQ * DIM / 4; idx += 256) {
        const int q = idx >> 5, seg = idx & 31;           // 8-B granules
        const int slot = (seg >> 1) ^ (q & 7);
        *(ushort4*)&sm.s.Q[q][slot * 8 + (seg & 1) * 4] =
            *(const ushort4*)(qb + (size_t)q * DIM + seg * 4);
    }
    if (tid < 128) sm.s.mk[tid] = dmask[(size_t)b * LD + c * 128 + tid];
    __syncthreads();

    // ---- per-token inverse norm (2 threads/token) ----
    {
        const int t2 = tid >> 1, hf = tid & 1;
        float ssum = 0.f;
        #pragma unroll
        for (int j = 0; j < 8; ++j) {
            const int slot = (hf * 8 + j) ^ (t2 & 7);
            bf16x8 v = *(const bf16x8*)&sm.s.C[t2][slot * 8];
            #pragma unroll
            for (int e = 0; e < 8; ++e) {
                float f = bf2f((unsigned short)v[e]);
                ssum += f * f;
            }
        }
        ssum += __shfl_xor(ssum, 1);
        if (hf == 0) sm.s.dinv[t2] = 1.0f / fmaxf(sqrtf(ssum), EPSF);
    }
    __syncthreads();

    // ---- sim GEMM: [32 q] x [32 tokens per wave], K=128 ----
    f32x4 sacc[2][2];
    #pragma unroll
    for (int m = 0; m < 2; ++m)
        #pragma unroll
        for (int n = 0; n < 2; ++n)
            sacc[m][n] = (f32x4){0.f, 0.f, 0.f, 0.f};
    #pragma unroll
    for (int ks = 0; ks < 4; ++ks) {
        bf16x8 qa[2], cb[2];
        #pragma unroll
        for (int m = 0; m < 2; ++m) {
            const int row  = m * 16 + r15;
            const int slot = (ks * 4 + g) ^ (row & 7);
            qa[m] = *(const bf16x8*)&sm.s.Q[row][slot * 8];
        }
        #pragma unroll
        for (int n = 0; n < 2; ++n) {
            const int row  = w * 32 + n * 16 + r15;
            const int slot = (ks * 4 + g) ^ (row & 7);
            cb[n] = *(const bf16x8*)&sm.s.C[row][slot * 8];
        }
        #pragma unroll
        for (int m = 0; m < 2; ++m)
            #pragma unroll
            for (int n = 0; n < 2; ++n)
                sacc[m][n] = __builtin_amdgcn_mfma_f32_16x16x32_bf16(qa[m], cb[n], sacc[m][n], 0, 0, 0);
    }

    // ---- masked per-query max over this wave's 32 tokens ----
    #pragma unroll
    for (int m = 0; m < 2; ++m) {
        #pragma unroll
        for (int r = 0; r < 4; ++r) {
            float vmax = -INFINITY;
            #pragma unroll
            for (int n = 0; n < 2; ++n) {
                const int t = w * 32 + n * 16 + r15;
                float v = sacc[m][n][r] * sm.s.dinv[t];
                v = sm.s.mk[t] ? v : -INFINITY;
                vmax = fmaxf(vmax, v);
            }
            #pragma unroll
            for (int off = 1; off < 16; off <<= 1)
                vmax = fmaxf(vmax, __shfl_xor(vmax, off));
            if (r15 == 0) sm.s.pmax[m * 16 + g * 4 + r][w] = vmax;
        }
    }
    __syncthreads();
    if (tid < 32) {
        float m0 = fmaxf(fmaxf(sm.s.pmax[tid][0], sm.s.pmax[tid][1]),
                         fmaxf(sm.s.pmax[tid][2], sm.s.pmax[tid][3]));
        part[(size_t)blk * 32 + tid] = m0;
    }
}

// ---------------- final: max over chunks, sum over queries ----------------
__global__ __launch_bounds__(64) void final_kernel(
    const float* __restrict__ part, float* __restrict__ out)
{
    const int b = blockIdx.x;
    const int q = threadIdx.x & 31;
    const float* p = part + (size_t)b * 128;
    float m = fmaxf(fmaxf(p[q], p[32 + q]), fmaxf(p[64 + q], p[96 + q]));
    #pragma unroll
    for (int off = 1; off < 32; off <<= 1) m += __shfl_xor(m, off);
    if (threadIdx.x == 0) out[b] = m;
}

extern "C" void kernel_launch(void* const* d_in, const int* in_sizes, int n_in,
                              void* d_out, int out_size, void* d_ws, size_t ws_size,
                              hipStream_t stream) {
    const float* qh    = (const float*)d_in[0];
    const float* dh    = (const float*)d_in[1];
    const float* W     = (const float*)d_in[2];
    const int*   dmask = (const int*)d_in[3];
    const int*   ppq   = (const int*)d_in[4];
    float*       out   = (float*)d_out;

    unsigned short* wsW  = (unsigned short*)d_ws;                       // 24*2*128*32*2 B = 384 KB
    unsigned short* qn   = (unsigned short*)((char*)d_ws + 393216);     // 256 KB
    float*          part = (float*)((char*)d_ws + 393216 + 262144);    // 128 KB

    const int nq = in_sizes[0] / H;      // Bq*Lq = 1024 query tokens
    const int Bd = out_size;             // 256 docs

    wconv_kernel<<<NT, 256, 0, stream>>>(W, wsW);
    qproj_kernel<<<nq, 128, 0, stream>>>(qh, W, qn);
    docgemm_kernel<<<Bd * 4, 256, 0, stream>>>(dh, wsW, dmask, qn, part, ppq);
    final_kernel<<<Bd, 64, 0, stream>>>(part, out);
}

// Round 4
// 144.228 us; speedup vs baseline: 7.1198x; 1.6574x over previous
//
#include <hip/hip_runtime.h>
#include <math.h>

#define H    768
#define NT   24           // H/32 K-tiles
#define DIM  128
#define LQ   32
#define LD   512
#define BM   256          // tokens per block
#define EPSF 1e-12f

typedef _Float16 f16x8 __attribute__((ext_vector_type(8)));
typedef _Float16 f16x4 __attribute__((ext_vector_type(4)));
typedef float    f32x4 __attribute__((ext_vector_type(4)));

static __device__ __forceinline__ unsigned short h2u(_Float16 h) {
    return __builtin_bit_cast(unsigned short, h);
}

#define GLOAD_LDS16(g, l) __builtin_amdgcn_global_load_lds(                    \
    (const __attribute__((address_space(1))) unsigned int*)(const void*)(g),   \
    (__attribute__((address_space(3))) unsigned int*)(void*)(l), 16, 0, 0)

// ---------------- W -> f16 hi/lo, pre-swizzled per K-tile ----------------
// ws layout: [ks][hi/lo][row 0..127][32 cols, granule-swizzled] (16 KB / tile)
__global__ __launch_bounds__(256) void wconv_kernel(
    const float* __restrict__ W, unsigned short* __restrict__ wsW)
{
    const int ks  = blockIdx.x;
    const int tid = threadIdx.x;
    #pragma unroll 4
    for (int i = 0; i < 16; ++i) {
        const int idx = tid + i * 256;          // 0..4095
        const int row = idx >> 5, col = idx & 31;
        const float x = W[(size_t)row * H + ks * 32 + col];
        const _Float16 hi = (_Float16)x;
        const _Float16 lo = (_Float16)(x - (float)hi);
        const int colS = (((col >> 3) ^ ((row >> 1) & 3)) << 3) | (col & 7);
        wsW[(((size_t)ks * 2 + 0) * 128 + row) * 32 + colS] = h2u(hi);
        wsW[(((size_t)ks * 2 + 1) * 128 + row) * 32 + colS] = h2u(lo);
    }
}

// ---------------- query projection + L2 normalize -> f16 ----------------
// 4 tokens per block: W read 4x less often than 1-token-per-block.
__global__ __launch_bounds__(128) void qproj_kernel(
    const float* __restrict__ qh, const float* __restrict__ W,
    unsigned short* __restrict__ qn)
{
    const int blk = blockIdx.x;
    const int tid = threadIdx.x;
    __shared__ float rows[4][H];
    __shared__ float red[128];

    const float4* src = (const float4*)(qh + (size_t)blk * 4 * H);
    float4*       dst = (float4*)&rows[0][0];
    for (int i = tid; i < 4 * H / 4; i += 128) dst[i] = src[i];
    __syncthreads();

    const float4* w4 = (const float4*)(W + (size_t)tid * H);
    float acc[4] = {0.f, 0.f, 0.f, 0.f};
    for (int i = 0; i < H / 4; ++i) {
        float4 w = w4[i];
        #pragma unroll
        for (int j = 0; j < 4; ++j) {
            float4 x = ((const float4*)&rows[j][0])[i];
            acc[j] += w.x*x.x + w.y*x.y + w.z*x.z + w.w*x.w;
        }
    }
    #pragma unroll
    for (int j = 0; j < 4; ++j) {
        red[tid] = acc[j] * acc[j];
        __syncthreads();
        for (int s = 64; s > 0; s >>= 1) {
            if (tid < s) red[tid] += red[tid + s];
            __syncthreads();
        }
        const float inv = 1.0f / fmaxf(sqrtf(red[0]), EPSF);
        qn[((size_t)blk * 4 + j) * DIM + tid] = h2u((_Float16)(acc[j] * inv));
        __syncthreads();
    }
}

// ---------------- doc: pipelined f16 MFMA projection + norm + masked MaxSim --
struct Smem {
    union {
        struct {  // GEMM stage: 32 KB A + 32 KB W
            unsigned short A[2][BM][32];
            unsigned short Wt[2][2][128][32];
        } g;
        unsigned short C[BM][DIM];   // epilogue: 64 KB (overlaps GEMM region)
    } u;
    float         pnorm[2][BM];      // 2 KB
    unsigned char mk[BM];            // 256 B
    float         pmax[LQ][8];       // 1 KB
};

__global__ __launch_bounds__(512, 4) void docgemm_kernel(
    const float* __restrict__ dh, const unsigned short* __restrict__ wsW,
    const int* __restrict__ dmask, const unsigned short* __restrict__ qn,
    float* __restrict__ part, const int* __restrict__ ppq_p)
{
    __shared__ Smem sm;
    const int blk = blockIdx.x;
    const int b   = blk >> 1;        // doc
    const int c   = blk & 1;         // 256-token chunk
    const int tid = threadIdx.x;
    const int w   = tid >> 6;        // wave 0..7
    const int wm  = w >> 1, wn = w & 1;
    const int l   = tid & 63;
    const int g   = l >> 4;
    const int r15 = l & 15;
    const int ppq = ppq_p[0];

    // A staging geometry: thread -> rows r0 + i*64 (i=0..3), 4-float segment seg0
    const int r0   = tid >> 3;       // 0..63
    const int seg0 = tid & 7;        // 0..7 (float4 within 32-wide row)
    const int aswz = (r0 >> 1) & 3;  // same for all i (64 ≡ 0 mod 4 in (row>>1)&3)
    const int coli = (((seg0 >> 1) ^ aswz) << 3) | ((seg0 & 1) << 2);

    const float* Abase = dh + ((size_t)b * LD + (size_t)c * BM) * H;

    f32x4 acc[4][4];
    #pragma unroll
    for (int m = 0; m < 4; ++m)
        #pragma unroll
        for (int n = 0; n < 4; ++n)
            acc[m][n] = (f32x4){0.f, 0.f, 0.f, 0.f};

    float4 avA[4];

    // ---- prologue: W(0) first (oldest vm ops), A(0) -> convert, A(1) in flight
    {
        const char* wt   = (const char*)wsW;
        char*       wdst = (char*)&sm.u.g.Wt[0][0][0][0];
        GLOAD_LDS16(wt + tid * 16,        wdst + (w * 64) * 16);
        GLOAD_LDS16(wt + 8192 + tid * 16, wdst + 8192 + (w * 64) * 16);
        __builtin_amdgcn_sched_barrier(0);
        #pragma unroll
        for (int i = 0; i < 4; ++i)
            avA[i] = *(const float4*)(Abase + (size_t)(r0 + i * 64) * H + seg0 * 4);
        #pragma unroll
        for (int i = 0; i < 4; ++i) {
            const int row = r0 + i * 64;
            f16x4 h;
            h[0] = (_Float16)avA[i].x; h[1] = (_Float16)avA[i].y;
            h[2] = (_Float16)avA[i].z; h[3] = (_Float16)avA[i].w;
            *(f16x4*)&sm.u.g.A[0][row][coli] = h;
        }
        #pragma unroll
        for (int i = 0; i < 4; ++i)
            avA[i] = *(const float4*)(Abase + (size_t)(r0 + i * 64) * H + 32 + seg0 * 4);
        asm volatile("s_waitcnt vmcnt(4) lgkmcnt(0)" ::: "memory");
        __builtin_amdgcn_sched_barrier(0);
        __builtin_amdgcn_s_barrier();
        __builtin_amdgcn_sched_barrier(0);
    }

    // ---- main K-loop: counted vmcnt keeps A(t+2) loads in flight across barrier
    for (int t = 0; t < NT; ++t) {
        const int cur = t & 1, nxt = cur ^ 1;

        if (t + 1 < NT) {  // W(t+1) via global_load_lds — issued FIRST (oldest)
            const char* wt   = (const char*)wsW + (size_t)(t + 1) * 16384;
            char*       wdst = (char*)&sm.u.g.Wt[nxt][0][0][0];
            GLOAD_LDS16(wt + tid * 16,        wdst + (w * 64) * 16);
            GLOAD_LDS16(wt + 8192 + tid * 16, wdst + 8192 + (w * 64) * 16);
        }
        __builtin_amdgcn_sched_barrier(0);   // pin: W issue precedes A issue

        // fragments + MFMA (hi + lo W terms)
        f16x8 ah[4];
        #pragma unroll
        for (int m = 0; m < 4; ++m) {
            const int row = wm * 64 + m * 16 + r15;
            const int sl  = (g ^ ((row >> 1) & 3)) * 8;
            ah[m] = *(const f16x8*)&sm.u.g.A[cur][row][sl];
        }
        __builtin_amdgcn_s_setprio(1);
        #pragma unroll
        for (int n = 0; n < 4; ++n) {
            const int row = wn * 64 + n * 16 + r15;
            const int sl  = (g ^ ((row >> 1) & 3)) * 8;
            f16x8 bh = *(const f16x8*)&sm.u.g.Wt[cur][0][row][sl];
            f16x8 bl = *(const f16x8*)&sm.u.g.Wt[cur][1][row][sl];
            #pragma unroll
            for (int m = 0; m < 4; ++m)
                acc[m][n] = __builtin_amdgcn_mfma_f32_16x16x32_f16(ah[m], bh, acc[m][n], 0, 0, 0);
            #pragma unroll
            for (int m = 0; m < 4; ++m)
                acc[m][n] = __builtin_amdgcn_mfma_f32_16x16x32_f16(ah[m], bl, acc[m][n], 0, 0, 0);
        }
        __builtin_amdgcn_s_setprio(0);

        if (t + 1 < NT) {  // convert avA (tile t+1 data) -> LDS buf[nxt]
            #pragma unroll
            for (int i = 0; i < 4; ++i) {
                const int row = r0 + i * 64;
                f16x4 h;
                h[0] = (_Float16)avA[i].x; h[1] = (_Float16)avA[i].y;
                h[2] = (_Float16)avA[i].z; h[3] = (_Float16)avA[i].w;
                *(f16x4*)&sm.u.g.A[nxt][row][coli] = h;
            }
        }
        if (t + 2 < NT) {  // issue A(t+2) — youngest, allowed to stay in flight
            const int k0n = (t + 2) * 32;
            #pragma unroll
            for (int i = 0; i < 4; ++i)
                avA[i] = *(const float4*)(Abase + (size_t)(r0 + i * 64) * H + k0n + seg0 * 4);
        }

        if (t + 2 < NT) {
            asm volatile("s_waitcnt vmcnt(4) lgkmcnt(0)" ::: "memory");
        } else {
            asm volatile("s_waitcnt vmcnt(0) lgkmcnt(0)" ::: "memory");
        }
        __builtin_amdgcn_sched_barrier(0);
        __builtin_amdgcn_s_barrier();
        __builtin_amdgcn_sched_barrier(0);
    }

    // ---- epilogue 1: C -> LDS f16 (swizzled), per-token norms from registers
    #pragma unroll
    for (int m = 0; m < 4; ++m) {
        const int tokb = wm * 64 + m * 16 + g * 4;
        #pragma unroll
        for (int n = 0; n < 4; ++n) {
            const int dim = wn * 64 + n * 16 + r15;
            #pragma unroll
            for (int r = 0; r < 4; ++r) {
                const int tok  = tokb + r;
                const int slot = (dim >> 3) ^ (tok & 7);
                sm.u.C[tok][slot * 8 + (dim & 7)] = h2u((_Float16)acc[m][n][r]);
            }
        }
    }
    #pragma unroll
    for (int m = 0; m < 4; ++m) {
        #pragma unroll
        for (int r = 0; r < 4; ++r) {
            float s = 0.f;
            #pragma unroll
            for (int n = 0; n < 4; ++n) s += acc[m][n][r] * acc[m][n][r];
            s += __shfl_xor(s, 1); s += __shfl_xor(s, 2);
            s += __shfl_xor(s, 4); s += __shfl_xor(s, 8);
            if (r15 == 0) sm.pnorm[wn][wm * 64 + m * 16 + g * 4 + r] = s;
        }
    }
    if (tid < BM) sm.mk[tid] = (unsigned char)(dmask[(size_t)b * LD + c * BM + tid] != 0);
    __syncthreads();

    // ---- epilogue 2: sim GEMM [32 q] x [32 tokens per wave], K=128, Q from global
    const unsigned short* qb = qn + (size_t)(b / ppq) * LQ * DIM;
    const int t0 = w * 32 + r15, t1 = t0 + 16;
    const float inv0 = 1.0f / fmaxf(sqrtf(sm.pnorm[0][t0] + sm.pnorm[1][t0]), EPSF);
    const float inv1 = 1.0f / fmaxf(sqrtf(sm.pnorm[0][t1] + sm.pnorm[1][t1]), EPSF);

    f32x4 sacc[2][2];
    #pragma unroll
    for (int m = 0; m < 2; ++m)
        #pragma unroll
        for (int n = 0; n < 2; ++n)
            sacc[m][n] = (f32x4){0.f, 0.f, 0.f, 0.f};
    #pragma unroll
    for (int ks = 0; ks < 4; ++ks) {
        f16x8 qa[2], cb[2];
        #pragma unroll
        for (int m = 0; m < 2; ++m)
            qa[m] = *(const f16x8*)(qb + (size_t)(m * 16 + r15) * DIM + ks * 32 + g * 8);
        #pragma unroll
        for (int n = 0; n < 2; ++n) {
            const int row  = w * 32 + n * 16 + r15;
            const int slot = (ks * 4 + g) ^ (row & 7);
            cb[n] = *(const f16x8*)&sm.u.C[row][slot * 8];
        }
        #pragma unroll
        for (int m = 0; m < 2; ++m)
            #pragma unroll
            for (int n = 0; n < 2; ++n)
                sacc[m][n] = __builtin_amdgcn_mfma_f32_16x16x32_f16(qa[m], cb[n], sacc[m][n], 0, 0, 0);
    }

    // ---- masked per-query max over this wave's 32 tokens
    const int m0 = sm.mk[t0], m1 = sm.mk[t1];
    #pragma unroll
    for (int m = 0; m < 2; ++m) {
        #pragma unroll
        for (int r = 0; r < 4; ++r) {
            float v0 = m0 ? sacc[m][0][r] * inv0 : -INFINITY;
            float v1 = m1 ? sacc[m][1][r] * inv1 : -INFINITY;
            float vmax = fmaxf(v0, v1);
            vmax = fmaxf(vmax, __shfl_xor(vmax, 1));
            vmax = fmaxf(vmax, __shfl_xor(vmax, 2));
            vmax = fmaxf(vmax, __shfl_xor(vmax, 4));
            vmax = fmaxf(vmax, __shfl_xor(vmax, 8));
            if (r15 == 0) sm.pmax[m * 16 + g * 4 + r][w] = vmax;
        }
    }
    __syncthreads();
    if (tid < LQ) {
        float mv = sm.pmax[tid][0];
        #pragma unroll
        for (int j = 1; j < 8; ++j) mv = fmaxf(mv, sm.pmax[tid][j]);
        part[(size_t)blk * 32 + tid] = mv;
    }
}

// ---------------- final: max over 2 chunks, sum over queries ----------------
__global__ __launch_bounds__(64) void final_kernel(
    const float* __restrict__ part, float* __restrict__ out)
{
    const int b = blockIdx.x;
    const int q = threadIdx.x & 31;
    const float* p = part + (size_t)b * 64;
    float m = fmaxf(p[q], p[32 + q]);
    #pragma unroll
    for (int off = 1; off < 32; off <<= 1) m += __shfl_xor(m, off);
    if (threadIdx.x == 0) out[b] = m;
}

extern "C" void kernel_launch(void* const* d_in, const int* in_sizes, int n_in,
                              void* d_out, int out_size, void* d_ws, size_t ws_size,
                              hipStream_t stream) {
    const float* qh    = (const float*)d_in[0];
    const float* dh    = (const float*)d_in[1];
    const float* W     = (const float*)d_in[2];
    const int*   dmask = (const int*)d_in[3];
    const int*   ppq   = (const int*)d_in[4];
    float*       out   = (float*)d_out;

    unsigned short* wsW  = (unsigned short*)d_ws;                     // 384 KB
    unsigned short* qn   = (unsigned short*)((char*)d_ws + 393216);   // 256 KB
    float*          part = (float*)((char*)d_ws + 393216 + 262144);   // 64 KB

    const int nq = in_sizes[0] / H;      // 1024 query tokens
    const int Bd = out_size;             // 256 docs

    wconv_kernel<<<NT, 256, 0, stream>>>(W, wsW);
    qproj_kernel<<<nq / 4, 128, 0, stream>>>(qh, W, qn);
    docgemm_kernel<<<Bd * 2, 512, 0, stream>>>(dh, wsW, dmask, qn, part, ppq);
    final_kernel<<<Bd, 64, 0, stream>>>(part, out);
}